// Round 1
// baseline (648.157 us; speedup 1.0000x reference)
//
#include <hip/hip_runtime.h>

#define NHID 128
#define BM   64    // edge-tile (N-dim of transposed GEMM)
#define LDE  136   // 128 + 8 pad: row stride 272 B = 17*16 B (odd multiple of 16)

typedef __attribute__((ext_vector_type(8))) short short8;
typedef __attribute__((ext_vector_type(4))) float f32x4;
typedef __attribute__((ext_vector_type(4))) unsigned short ushort4v;

__device__ inline unsigned short f2bf(float f) {
    unsigned int u = __float_as_uint(f);
    u += 0x7fffu + ((u >> 16) & 1u);   // round-to-nearest-even
    return (unsigned short)(u >> 16);
}
__device__ inline float bf2f(unsigned short h) {
    return __uint_as_float(((unsigned int)h) << 16);
}

// ---- prep: convert/transpose weights to bf16, detect int64 edge_index ----
// wtp [256][128]: rows 0..127 = W1[k][n] by out-feat row, rows 128..255 = W2
// wt3 [128][128]: W3 by out-feat row    wte [128][128]: W_edge by out-feat row
__global__ void prep_kernel(const float* __restrict__ Wm, const float* __restrict__ We,
                            const int* __restrict__ eidx_raw,
                            unsigned short* __restrict__ wtp,
                            unsigned short* __restrict__ wt3,
                            unsigned short* __restrict__ wte,
                            int* __restrict__ flag) {
    int i = blockIdx.x * 256 + threadIdx.x;
    if (i < 256 * NHID) {
        int nn = i >> 7, k = i & 127;
        float v = (nn < 128) ? Wm[k * NHID + nn] : Wm[(128 + k) * NHID + (nn - 128)];
        wtp[i] = f2bf(v);
    }
    if (i < NHID * NHID) {
        int n = i >> 7, k = i & 127;
        wt3[i] = f2bf(Wm[(256 + k) * NHID + n]);
        wte[i] = f2bf(We[k * NHID + n]);
    }
    if (blockIdx.x == 0) {
        __shared__ int nz;
        if (threadIdx.x == 0) nz = 0;
        __syncthreads();
        if (threadIdx.x < 64) {
            if (eidx_raw[threadIdx.x * 2 + 1] != 0) atomicAdd(&nz, 1);
        }
        __syncthreads();
        if (threadIdx.x == 0) flag[0] = (nz == 0) ? 1 : 0;   // 1 => int64
    }
}

// ---- node projection (transposed): Xp[n][0:128]=x[n]@W1, Xp[n][128:256]=x[n]@W2 ----
// D[feat][node] = W[feat][k] * x[node][k]; C-layout: lane=node, reg=4 consecutive feats
__global__ __launch_bounds__(256, 6) void proj_kernel(
    const float* __restrict__ x, const unsigned short* __restrict__ wtp,
    unsigned short* __restrict__ xp, int N)
{
    __shared__ __align__(16) unsigned short sX[BM * LDE];

    const int tid  = threadIdx.x;
    const int lane = tid & 63;
    const int wave = tid >> 6;
    const int wm   = wave >> 1, wn = wave & 1;
    const int l15  = lane & 15, l4 = lane >> 4;
    const int n0   = blockIdx.x * BM;
    const int half = blockIdx.y;          // 0: W1, 1: W2

    // stage x rows fp32 -> bf16 (4 threads per row, 32 cols each)
    {
        const int srow = tid >> 2, sc0 = (tid & 3) * 32;
        int n = n0 + srow; if (n >= N) n = N - 1;
        const float4* sp = (const float4*)(x + (size_t)n * NHID + sc0);
        #pragma unroll
        for (int j = 0; j < 4; ++j) {
            float4 f0 = sp[2 * j], f1 = sp[2 * j + 1];
            short8 hv;
            hv[0] = (short)f2bf(f0.x); hv[1] = (short)f2bf(f0.y);
            hv[2] = (short)f2bf(f0.z); hv[3] = (short)f2bf(f0.w);
            hv[4] = (short)f2bf(f1.x); hv[5] = (short)f2bf(f1.y);
            hv[6] = (short)f2bf(f1.z); hv[7] = (short)f2bf(f1.w);
            *(short8*)&sX[srow * LDE + sc0 + j * 8] = hv;
        }
    }
    __syncthreads();

    f32x4 acc[4][2];
    #pragma unroll
    for (int mt = 0; mt < 4; ++mt)
        #pragma unroll
        for (int nt = 0; nt < 2; ++nt) acc[mt][nt] = (f32x4){0.f, 0.f, 0.f, 0.f};

    const unsigned short* wb = wtp + (size_t)half * NHID * NHID;
    #pragma unroll
    for (int kk = 0; kk < 4; ++kk) {
        short8 af[4], bfr[2];
        #pragma unroll
        for (int mt = 0; mt < 4; ++mt)
            af[mt] = *(const short8*)(wb + (wm * 64 + mt * 16 + l15) * NHID + kk * 32 + l4 * 8);
        #pragma unroll
        for (int nt = 0; nt < 2; ++nt)
            bfr[nt] = *(const short8*)(&sX[(wn * 32 + nt * 16 + l15) * LDE + kk * 32 + l4 * 8]);
        #pragma unroll
        for (int mt = 0; mt < 4; ++mt)
            #pragma unroll
            for (int nt = 0; nt < 2; ++nt)
                acc[mt][nt] = __builtin_amdgcn_mfma_f32_16x16x32_bf16(
                    af[mt], bfr[nt], acc[mt][nt], 0, 0, 0);
    }

    // write: each thread owns 4 consecutive feats of node l15 -> ushort4 stores
    #pragma unroll
    for (int nt = 0; nt < 2; ++nt) {
        int n = n0 + wn * 32 + nt * 16 + l15;
        if (n < N) {
            #pragma unroll
            for (int mt = 0; mt < 4; ++mt) {
                int fb = wm * 64 + mt * 16 + l4 * 4;
                ushort4v v;
                #pragma unroll
                for (int r = 0; r < 4; ++r) v[r] = f2bf(acc[mt][nt][r]);
                *(ushort4v*)(xp + (size_t)n * 256 + half * NHID + fb) = v;
            }
        }
    }
}

// ---- main: per 64-edge tile, transposed GEMMs ----
// D[feat][edge]: lane = edge, regs = 4 consecutive feats -> vectorized gather/store
__global__ __launch_bounds__(256, 6) void edge_conv_kernel(
    const float* __restrict__ eattr,
    const int* __restrict__ ip,
    const float* __restrict__ bmsg, const float* __restrict__ bedge,
    const unsigned short* __restrict__ wt3,
    const unsigned short* __restrict__ wte,
    const unsigned short* __restrict__ xp,
    const int* __restrict__ flag,
    float* __restrict__ out, int E)
{
    __shared__ __align__(16) unsigned short sEA[BM * LDE];  // 17408 B
    __shared__ int sIdx[2 * BM];                            // 512 B

    const int tid  = threadIdx.x;
    const int lane = tid & 63;
    const int wave = tid >> 6;
    const int wm   = wave >> 1, wn = wave & 1;
    const int l15  = lane & 15, l4 = lane >> 4;
    const int e0   = blockIdx.x * BM;
    const int is64 = flag[0];

    // edge indices (low words if int64)
    if (tid < 2 * BM) {
        int e = e0 + (tid & (BM - 1)); if (e >= E) e = E - 1;
        long long off = (tid < BM) ? (long long)e : ((long long)E + e);
        sIdx[tid] = is64 ? ip[2 * off] : ip[off];
    }

    // stage edge_attr fp32 -> bf16 (4 threads per row, 32 cols each)
    {
        const int srow = tid >> 2, sc0 = (tid & 3) * 32;
        int e = e0 + srow; if (e >= E) e = E - 1;
        const float4* sp = (const float4*)(eattr + (size_t)e * NHID + sc0);
        #pragma unroll
        for (int j = 0; j < 4; ++j) {
            float4 f0 = sp[2 * j], f1 = sp[2 * j + 1];
            short8 hv;
            hv[0] = (short)f2bf(f0.x); hv[1] = (short)f2bf(f0.y);
            hv[2] = (short)f2bf(f0.z); hv[3] = (short)f2bf(f0.w);
            hv[4] = (short)f2bf(f1.x); hv[5] = (short)f2bf(f1.y);
            hv[6] = (short)f2bf(f1.z); hv[7] = (short)f2bf(f1.w);
            *(short8*)&sEA[srow * LDE + sc0 + j * 8] = hv;
        }
    }
    __syncthreads();

    f32x4 acc[4][2];
    #pragma unroll
    for (int mt = 0; mt < 4; ++mt)
        #pragma unroll
        for (int nt = 0; nt < 2; ++nt) acc[mt][nt] = (f32x4){0.f, 0.f, 0.f, 0.f};

    // GEMM1': D = W3 * eattr^T   (A = wt3 rows from global/L2, B = sEA rows from LDS)
    #pragma unroll
    for (int kk = 0; kk < 4; ++kk) {
        short8 af[4], bfr[2];
        #pragma unroll
        for (int mt = 0; mt < 4; ++mt)
            af[mt] = *(const short8*)(wt3 + (wm * 64 + mt * 16 + l15) * NHID + kk * 32 + l4 * 8);
        #pragma unroll
        for (int nt = 0; nt < 2; ++nt)
            bfr[nt] = *(const short8*)(&sEA[(wn * 32 + nt * 16 + l15) * LDE + kk * 32 + l4 * 8]);
        #pragma unroll
        for (int mt = 0; mt < 4; ++mt)
            #pragma unroll
            for (int nt = 0; nt < 2; ++nt)
                acc[mt][nt] = __builtin_amdgcn_mfma_f32_16x16x32_bf16(
                    af[mt], bfr[nt], acc[mt][nt], 0, 0, 0);
    }
    __syncthreads();   // all waves done reading sEA before epilogue rewrites it

    // epilogue 1: ea = edge_attr + relu(acc + b_msg + Xp1[row] + Xp2[col])
    // vectorized: per (nt) batch 8x ushort4 gathers (8 B each), rmw sEA as ushort4
    {
        f32x4 bm4[4];
        #pragma unroll
        for (int mt = 0; mt < 4; ++mt)
            bm4[mt] = *(const f32x4*)(bmsg + wm * 64 + mt * 16 + l4 * 4);
        #pragma unroll
        for (int nt = 0; nt < 2; ++nt) {
            int eL = wn * 32 + nt * 16 + l15;
            int nr = sIdx[eL];
            int nc = sIdx[BM + eL];
            ushort4v p1[4], p2[4];
            #pragma unroll
            for (int mt = 0; mt < 4; ++mt)
                p1[mt] = *(const ushort4v*)(xp + (size_t)nr * 256 + wm * 64 + mt * 16 + l4 * 4);
            #pragma unroll
            for (int mt = 0; mt < 4; ++mt)
                p2[mt] = *(const ushort4v*)(xp + (size_t)nc * 256 + 128 + wm * 64 + mt * 16 + l4 * 4);
            #pragma unroll
            for (int mt = 0; mt < 4; ++mt) {
                int fb = wm * 64 + mt * 16 + l4 * 4;
                ushort4v old = *(ushort4v*)(&sEA[eL * LDE + fb]);
                ushort4v nw;
                #pragma unroll
                for (int r = 0; r < 4; ++r) {
                    float m = acc[mt][nt][r] + bm4[mt][r]
                            + bf2f(p1[mt][r]) + bf2f(p2[mt][r]);
                    m = fmaxf(m, 0.f);
                    nw[r] = f2bf(bf2f(old[r]) + m);
                    acc[mt][nt][r] = 0.f;
                }
                *(ushort4v*)(&sEA[eL * LDE + fb]) = nw;
            }
        }
    }
    __syncthreads();

    // GEMM2: D = W_edge * ea^T
    #pragma unroll
    for (int kk = 0; kk < 4; ++kk) {
        short8 af[4], bfr[2];
        #pragma unroll
        for (int mt = 0; mt < 4; ++mt)
            af[mt] = *(const short8*)(wte + (wm * 64 + mt * 16 + l15) * NHID + kk * 32 + l4 * 8);
        #pragma unroll
        for (int nt = 0; nt < 2; ++nt)
            bfr[nt] = *(const short8*)(&sEA[(wn * 32 + nt * 16 + l15) * LDE + kk * 32 + l4 * 8]);
        #pragma unroll
        for (int mt = 0; mt < 4; ++mt)
            #pragma unroll
            for (int nt = 0; nt < 2; ++nt)
                acc[mt][nt] = __builtin_amdgcn_mfma_f32_16x16x32_bf16(
                    af[mt], bfr[nt], acc[mt][nt], 0, 0, 0);
    }

    // epilogue 2: out = relu(acc + b_edge), float4 stores (4 consecutive feats/lane)
    {
        f32x4 be4[4];
        #pragma unroll
        for (int mt = 0; mt < 4; ++mt)
            be4[mt] = *(const f32x4*)(bedge + wm * 64 + mt * 16 + l4 * 4);
        #pragma unroll
        for (int nt = 0; nt < 2; ++nt) {
            int eL = wn * 32 + nt * 16 + l15;
            int e  = e0 + eL;
            if (e < E) {
                #pragma unroll
                for (int mt = 0; mt < 4; ++mt) {
                    int fb = wm * 64 + mt * 16 + l4 * 4;
                    f32x4 v;
                    #pragma unroll
                    for (int r = 0; r < 4; ++r)
                        v[r] = fmaxf(acc[mt][nt][r] + be4[mt][r], 0.f);
                    *(f32x4*)(out + (size_t)e * NHID + fb) = v;
                }
            }
        }
    }
}

extern "C" void kernel_launch(void* const* d_in, const int* in_sizes, int n_in,
                              void* d_out, int out_size, void* d_ws, size_t ws_size,
                              hipStream_t stream) {
    const float* x     = (const float*)d_in[0];
    const float* eattr = (const float*)d_in[1];
    const int*   eidx  = (const int*)d_in[2];
    const float* Wm    = (const float*)d_in[3];
    const float* bm    = (const float*)d_in[4];
    const float* We    = (const float*)d_in[5];
    const float* be    = (const float*)d_in[6];
    float* out = (float*)d_out;

    const int N = in_sizes[0] / NHID;
    const int E = in_sizes[2] / 2;

    unsigned short* wtp = (unsigned short*)d_ws;        // 256*128
    unsigned short* wt3 = wtp + 256 * NHID;             // 128*128
    unsigned short* wte = wt3 + NHID * NHID;            // 128*128
    int* flag = (int*)(wte + NHID * NHID);
    unsigned short* xp  = (unsigned short*)(flag + 4);  // N*256 bf16 (~51 MB)

    prep_kernel<<<(256 * NHID + 255) / 256, 256, 0, stream>>>(Wm, We, eidx, wtp, wt3, wte, flag);

    dim3 pgrid((N + BM - 1) / BM, 2);
    proj_kernel<<<pgrid, 256, 0, stream>>>(x, wtp, xp, N);

    int nblocks = (E + BM - 1) / BM;
    edge_conv_kernel<<<nblocks, 256, 0, stream>>>(eattr, eidx, bm, be,
                                                  wt3, wte, xp, flag, out, E);
}

// Round 2
// 616.397 us; speedup vs baseline: 1.0515x; 1.0515x over previous
//
#include <hip/hip_runtime.h>

#define NHID 128
#define BM   128
#define LDE  136   // 128 + 8 pad: row stride 272 B = 17*16 B (odd multiple of 16)

typedef __attribute__((ext_vector_type(8))) short short8;
typedef __attribute__((ext_vector_type(4))) float f32x4;

__device__ inline unsigned short f2bf(float f) {
    unsigned int u = __float_as_uint(f);
    u += 0x7fffu + ((u >> 16) & 1u);   // round-to-nearest-even
    return (unsigned short)(u >> 16);
}
__device__ inline float bf2f(unsigned short h) {
    return __uint_as_float(((unsigned int)h) << 16);
}

// ---- prep: convert/transpose weights to bf16, detect int64 edge_index ----
__global__ void prep_kernel(const float* __restrict__ Wm, const float* __restrict__ We,
                            const int* __restrict__ eidx_raw,
                            unsigned short* __restrict__ wtp,
                            unsigned short* __restrict__ wt3,
                            unsigned short* __restrict__ wte,
                            int* __restrict__ flag) {
    int i = blockIdx.x * 256 + threadIdx.x;
    if (i < 256 * NHID) {
        int nn = i >> 7, k = i & 127;
        float v = (nn < 128) ? Wm[k * NHID + nn] : Wm[(128 + k) * NHID + (nn - 128)];
        wtp[i] = f2bf(v);
    }
    if (i < NHID * NHID) {
        int n = i >> 7, k = i & 127;
        wt3[i] = f2bf(Wm[(256 + k) * NHID + n]);
        wte[i] = f2bf(We[k * NHID + n]);
    }
    if (blockIdx.x == 0) {
        __shared__ int nz;
        if (threadIdx.x == 0) nz = 0;
        __syncthreads();
        if (threadIdx.x < 64) {
            if (eidx_raw[threadIdx.x * 2 + 1] != 0) atomicAdd(&nz, 1);
        }
        __syncthreads();
        if (threadIdx.x == 0) flag[0] = (nz == 0) ? 1 : 0;   // 1 => int64
    }
}

// ---- node projection: Xp[n][0:128]=x[n]@W1, Xp[n][128:256]=x[n]@W2 (bf16) ----
// (round-0 known-good version)
__global__ __launch_bounds__(256, 4) void proj_kernel(
    const float* __restrict__ x, const unsigned short* __restrict__ wtp,
    unsigned short* __restrict__ xp, int N)
{
    __shared__ __align__(16) unsigned short sX[BM * LDE];

    const int tid  = threadIdx.x;
    const int lane = tid & 63;
    const int wave = tid >> 6;
    const int wm   = wave >> 1, wn = wave & 1;
    const int l15  = lane & 15, l4 = lane >> 4;
    const int n0   = blockIdx.x * BM;
    const int half = blockIdx.y;          // 0: W1, 1: W2

    const int erow = tid >> 4, kg = tid & 15;
    #pragma unroll
    for (int p = 0; p < 8; ++p) {
        int el = p * 16 + erow;
        int n  = n0 + el; if (n >= N) n = N - 1;
        const float4* sp = (const float4*)(x + (size_t)n * NHID + kg * 8);
        float4 f0 = sp[0], f1 = sp[1];
        short8 hv;
        hv[0] = (short)f2bf(f0.x); hv[1] = (short)f2bf(f0.y);
        hv[2] = (short)f2bf(f0.z); hv[3] = (short)f2bf(f0.w);
        hv[4] = (short)f2bf(f1.x); hv[5] = (short)f2bf(f1.y);
        hv[6] = (short)f2bf(f1.z); hv[7] = (short)f2bf(f1.w);
        *(short8*)&sX[el * LDE + kg * 8] = hv;
    }
    __syncthreads();

    f32x4 acc[4][4];
    #pragma unroll
    for (int mt = 0; mt < 4; ++mt)
        #pragma unroll
        for (int nt = 0; nt < 4; ++nt) acc[mt][nt] = (f32x4){0.f,0.f,0.f,0.f};

    const unsigned short* wb = wtp + half * NHID * NHID;
    #pragma unroll
    for (int kk = 0; kk < 4; ++kk) {
        short8 af[4], bfr[4];
        #pragma unroll
        for (int mt = 0; mt < 4; ++mt) {
            int r = wm * 64 + mt * 16 + l15;
            af[mt] = *(const short8*)(&sX[r * LDE + kk * 32 + l4 * 8]);
        }
        #pragma unroll
        for (int nt = 0; nt < 4; ++nt) {
            int n = wn * 64 + nt * 16 + l15;
            bfr[nt] = *(const short8*)(wb + n * NHID + kk * 32 + l4 * 8);
        }
        #pragma unroll
        for (int mt = 0; mt < 4; ++mt)
            #pragma unroll
            for (int nt = 0; nt < 4; ++nt)
                acc[mt][nt] = __builtin_amdgcn_mfma_f32_16x16x32_bf16(
                    af[mt], bfr[nt], acc[mt][nt], 0, 0, 0);
    }

    #pragma unroll
    for (int mt = 0; mt < 4; ++mt) {
        int rbase = wm * 64 + mt * 16 + l4 * 4;
        #pragma unroll
        for (int r = 0; r < 4; ++r) {
            int n = n0 + rbase + r;
            if (n < N) {
                unsigned short* op = xp + (size_t)n * 256 + half * NHID + wn * 64 + l15;
                #pragma unroll
                for (int nt = 0; nt < 4; ++nt)
                    op[nt * 16] = f2bf(acc[mt][nt][r]);
            }
        }
    }
}

// ---- gather staging: one round = 32 edges (output-row group mt=i) ----
// sG layout: [which(2)][er(32)][16 chunks of 8 shorts], chunk order XOR-swizzled
// by (er&7) on the SOURCE side; LDS destination is linear (global_load_lds rule).
__device__ inline void gather_round(const unsigned short* __restrict__ xp,
                                    const int* sIdx, unsigned short* sG,
                                    int i, int wave, int lane) {
    #pragma unroll
    for (int it = 0; it < 4; ++it) {
        int c     = wave * 256 + it * 64 + lane;   // 1024 chunks of 16 B
        int which = c >> 9;
        int rem   = c & 511;
        int er    = rem >> 4;                      // 0..31 local edge
        int jpos  = rem & 15;                      // chunk slot in LDS
        int j     = jpos ^ (er & 7);               // source chunk (swizzle)
        int row   = (er >> 4) * 64 + i * 16 + (er & 15);
        int node  = sIdx[which * BM + row];
        const unsigned short* src = xp + (size_t)node * 256 + which * 128 + j * 8;
        unsigned short* dst = sG + (size_t)(wave * 4 + it) * 512;  // wave-uniform
        __builtin_amdgcn_global_load_lds(
            (const __attribute__((address_space(1))) unsigned int*)src,
            (__attribute__((address_space(3))) unsigned int*)dst, 16, 0, 0);
    }
}

// ---- main: per 128-edge tile ----
__global__ __launch_bounds__(256, 3) void edge_conv_kernel(
    const float* __restrict__ eattr,
    const int* __restrict__ ip,
    const float* __restrict__ bmsg, const float* __restrict__ bedge,
    const unsigned short* __restrict__ wt3,
    const unsigned short* __restrict__ wte,
    const unsigned short* __restrict__ xp,
    const int* __restrict__ flag,
    float* __restrict__ out, int E)
{
    __shared__ __align__(16) unsigned short sEA[BM * LDE];   // 34816 B
    __shared__ __align__(16) unsigned short sG[2 * 32 * 128]; // 16384 B
    __shared__ int sIdx[2 * BM];                             // 1024 B
    // total 52224 B -> 3 blocks/CU

    const int tid  = threadIdx.x;
    const int lane = tid & 63;
    const int wave = tid >> 6;
    const int wm   = wave >> 1, wn = wave & 1;
    const int l15  = lane & 15, l4 = lane >> 4;
    const int e0   = blockIdx.x * BM;
    const int is64 = flag[0];

    // edge indices (low words if int64)
    {
        int t = tid;
        if (t < BM) {
            int e = e0 + t; if (e >= E) e = E - 1;
            sIdx[t] = is64 ? ip[2 * (long long)e] : ip[e];
        } else {
            int e = e0 + (t - BM); if (e >= E) e = E - 1;
            long long off = (long long)E + e;
            sIdx[t] = is64 ? ip[2 * off] : ip[off];
        }
    }

    // stage edge_attr fp32 -> bf16 (non-temporal: single-use stream, keep L3 for xp)
    const int erow = tid >> 4, kg = tid & 15;
    #pragma unroll
    for (int p = 0; p < 8; ++p) {
        int el = p * 16 + erow;
        int e  = e0 + el; if (e >= E) e = E - 1;
        const f32x4* sp = (const f32x4*)(eattr + (size_t)e * NHID + kg * 8);
        f32x4 f0 = __builtin_nontemporal_load(sp);
        f32x4 f1 = __builtin_nontemporal_load(sp + 1);
        short8 hv;
        hv[0] = (short)f2bf(f0[0]); hv[1] = (short)f2bf(f0[1]);
        hv[2] = (short)f2bf(f0[2]); hv[3] = (short)f2bf(f0[3]);
        hv[4] = (short)f2bf(f1[0]); hv[5] = (short)f2bf(f1[1]);
        hv[6] = (short)f2bf(f1[2]); hv[7] = (short)f2bf(f1[3]);
        *(short8*)&sEA[el * LDE + kg * 8] = hv;
    }

    // hoist biases (hide latency under staging)
    float bm_[4], bb[4];
    #pragma unroll
    for (int nt = 0; nt < 4; ++nt) {
        bm_[nt] = bmsg[wn * 64 + nt * 16 + l15];
        bb[nt]  = bedge[wn * 64 + nt * 16 + l15];
    }

    __syncthreads();                      // B1: sEA + sIdx visible

    // prefetch gathers for round 0 (hidden under GEMM1)
    gather_round(xp, sIdx, sG, 0, wave, lane);

    f32x4 acc[4][4];
    #pragma unroll
    for (int mt = 0; mt < 4; ++mt)
        #pragma unroll
        for (int nt = 0; nt < 4; ++nt) acc[mt][nt] = (f32x4){0.f,0.f,0.f,0.f};

    // GEMM1': edge_attr @ W3   (K = 128)
    #pragma unroll
    for (int kk = 0; kk < 4; ++kk) {
        short8 af[4], bfr[4];
        #pragma unroll
        for (int mt = 0; mt < 4; ++mt) {
            int r = wm * 64 + mt * 16 + l15;
            af[mt] = *(const short8*)(&sEA[r * LDE + kk * 32 + l4 * 8]);
        }
        #pragma unroll
        for (int nt = 0; nt < 4; ++nt) {
            int n = wn * 64 + nt * 16 + l15;
            bfr[nt] = *(const short8*)(wt3 + n * NHID + kk * 32 + l4 * 8);
        }
        #pragma unroll
        for (int mt = 0; mt < 4; ++mt)
            #pragma unroll
            for (int nt = 0; nt < 4; ++nt)
                acc[mt][nt] = __builtin_amdgcn_mfma_f32_16x16x32_bf16(
                    af[mt], bfr[nt], acc[mt][nt], 0, 0, 0);
    }
    __syncthreads();   // B2: GEMM1 sEA reads done + gather(0) drained (vmcnt 0)

    // 4 rounds: epilogue1 rows mt=i -> barrier -> prefetch(i+1) + GEMM2 chunk i
    #pragma unroll
    for (int i = 0; i < 4; ++i) {
        // epilogue 1, rows of mt=i:
        // ea = edge_attr + relu(acc + b_msg + Xp1[row] + Xp2[col]) (gathered in sG)
        #pragma unroll
        for (int r = 0; r < 4; ++r) {
            int row = wm * 64 + i * 16 + l4 * 4 + r;
            int er  = wm * 16 + l4 * 4 + r;
            int eb  = er * 128;
            int ex  = er & 7;
            #pragma unroll
            for (int nt = 0; nt < 4; ++nt) {
                int f  = wn * 64 + nt * 16 + l15;
                int so = eb + ((((f >> 3) ^ ex) << 3) | (f & 7));
                float g = bf2f(sG[so]) + bf2f(sG[4096 + so]);  // p1 + p2, exact f32
                float m = acc[i][nt][r] + bm_[nt] + g;
                m = fmaxf(m, 0.f);
                int idx = row * LDE + f;
                sEA[idx] = f2bf(bf2f(sEA[idx]) + m);
                acc[i][nt][r] = 0.f;
            }
        }
        __syncthreads();   // sG(i) reads done; sEA rows-i visible to all waves

        if (i < 3) gather_round(xp, sIdx, sG, i + 1, wave, lane);

        // GEMM2 chunk i: rows mt=i of ea @ W_edge (contraction over all feats)
        #pragma unroll
        for (int kk = 0; kk < 4; ++kk) {
            short8 af = *(const short8*)(&sEA[(wm * 64 + i * 16 + l15) * LDE + kk * 32 + l4 * 8]);
            #pragma unroll
            for (int nt = 0; nt < 4; ++nt) {
                short8 bfr = *(const short8*)(wte + (wn * 64 + nt * 16 + l15) * NHID + kk * 32 + l4 * 8);
                acc[i][nt] = __builtin_amdgcn_mfma_f32_16x16x32_bf16(
                    af, bfr, acc[i][nt], 0, 0, 0);
            }
        }

        if (i < 3) __syncthreads();  // drain gather(i+1) before epilogue i+1
    }

    // epilogue 2: out = relu(acc + b_edge), non-temporal stores
    #pragma unroll
    for (int mt = 0; mt < 4; ++mt) {
        int rbase = wm * 64 + mt * 16 + l4 * 4;
        #pragma unroll
        for (int r = 0; r < 4; ++r) {
            int e = e0 + rbase + r;
            if (e < E) {
                float* op = out + (size_t)e * NHID + wn * 64 + l15;
                #pragma unroll
                for (int nt = 0; nt < 4; ++nt)
                    __builtin_nontemporal_store(fmaxf(acc[mt][nt][r] + bb[nt], 0.f),
                                                op + nt * 16);
            }
        }
    }
}

extern "C" void kernel_launch(void* const* d_in, const int* in_sizes, int n_in,
                              void* d_out, int out_size, void* d_ws, size_t ws_size,
                              hipStream_t stream) {
    const float* x     = (const float*)d_in[0];
    const float* eattr = (const float*)d_in[1];
    const int*   eidx  = (const int*)d_in[2];
    const float* Wm    = (const float*)d_in[3];
    const float* bm    = (const float*)d_in[4];
    const float* We    = (const float*)d_in[5];
    const float* be    = (const float*)d_in[6];
    float* out = (float*)d_out;

    const int N = in_sizes[0] / NHID;
    const int E = in_sizes[2] / 2;

    unsigned short* wtp = (unsigned short*)d_ws;        // 256*128
    unsigned short* wt3 = wtp + 256 * NHID;             // 128*128
    unsigned short* wte = wt3 + NHID * NHID;            // 128*128
    int* flag = (int*)(wte + NHID * NHID);
    unsigned short* xp  = (unsigned short*)(flag + 4);  // N*256 bf16 (~51 MB)

    prep_kernel<<<(256 * NHID + 255) / 256, 256, 0, stream>>>(Wm, We, eidx, wtp, wt3, wte, flag);

    dim3 pgrid((N + BM - 1) / BM, 2);
    proj_kernel<<<pgrid, 256, 0, stream>>>(x, wtp, xp, N);

    int nblocks = (E + BM - 1) / BM;
    edge_conv_kernel<<<nblocks, 256, 0, stream>>>(eattr, eidx, bm, be,
                                                  wt3, wte, xp, flag, out, E);
}

// Round 3
// 549.152 us; speedup vs baseline: 1.1803x; 1.1225x over previous
//
#include <hip/hip_runtime.h>

#define NHID 128
#define BM   128
#define LDE  136   // 128 + 8 pad: row stride 272 B = 17*16 B (odd multiple of 16)

typedef __attribute__((ext_vector_type(8))) short short8;
typedef __attribute__((ext_vector_type(4))) float f32x4;
typedef __attribute__((ext_vector_type(4))) unsigned short ushort4v;

__device__ inline unsigned short f2bf(float f) {
    unsigned int u = __float_as_uint(f);
    u += 0x7fffu + ((u >> 16) & 1u);   // round-to-nearest-even
    return (unsigned short)(u >> 16);
}
__device__ inline float bf2f(unsigned short h) {
    return __uint_as_float(((unsigned int)h) << 16);
}

// ---- prep: convert/transpose weights to bf16, detect int64 edge_index ----
__global__ void prep_kernel(const float* __restrict__ Wm, const float* __restrict__ We,
                            const int* __restrict__ eidx_raw,
                            unsigned short* __restrict__ wtp,
                            unsigned short* __restrict__ wt3,
                            unsigned short* __restrict__ wte,
                            int* __restrict__ flag) {
    int i = blockIdx.x * 256 + threadIdx.x;
    if (i < 256 * NHID) {
        int nn = i >> 7, k = i & 127;
        float v = (nn < 128) ? Wm[k * NHID + nn] : Wm[(128 + k) * NHID + (nn - 128)];
        wtp[i] = f2bf(v);
    }
    if (i < NHID * NHID) {
        int n = i >> 7, k = i & 127;
        wt3[i] = f2bf(Wm[(256 + k) * NHID + n]);
        wte[i] = f2bf(We[k * NHID + n]);
    }
    if (blockIdx.x == 0) {
        __shared__ int nz;
        if (threadIdx.x == 0) nz = 0;
        __syncthreads();
        if (threadIdx.x < 64) {
            if (eidx_raw[threadIdx.x * 2 + 1] != 0) atomicAdd(&nz, 1);
        }
        __syncthreads();
        if (threadIdx.x == 0) flag[0] = (nz == 0) ? 1 : 0;   // 1 => int64
    }
}

// ---- node projection: Xp[n] halves hold x[n]@W1 / x[n]@W2 (bf16) ----
// PERMUTED feature layout within each 64-feat half: offset = l15*4 + nt
// (fragment-contiguous: one ushort4 per (mt,r) write, one ushort4 per gather)
__global__ __launch_bounds__(256, 4) void proj_kernel(
    const float* __restrict__ x, const unsigned short* __restrict__ wtp,
    unsigned short* __restrict__ xp, int N)
{
    __shared__ __align__(16) unsigned short sX[BM * LDE];

    const int tid  = threadIdx.x;
    const int lane = tid & 63;
    const int wave = tid >> 6;
    const int wm   = wave >> 1, wn = wave & 1;
    const int l15  = lane & 15, l4 = lane >> 4;
    const int n0   = blockIdx.x * BM;
    const int half = blockIdx.y;          // 0: W1, 1: W2

    // stage x rows fp32 -> bf16
    const int erow = tid >> 4, kg = tid & 15;
    #pragma unroll
    for (int p = 0; p < 8; ++p) {
        int el = p * 16 + erow;
        int n  = n0 + el; if (n >= N) n = N - 1;
        const float4* sp = (const float4*)(x + (size_t)n * NHID + kg * 8);
        float4 f0 = sp[0], f1 = sp[1];
        short8 hv;
        hv[0] = (short)f2bf(f0.x); hv[1] = (short)f2bf(f0.y);
        hv[2] = (short)f2bf(f0.z); hv[3] = (short)f2bf(f0.w);
        hv[4] = (short)f2bf(f1.x); hv[5] = (short)f2bf(f1.y);
        hv[6] = (short)f2bf(f1.z); hv[7] = (short)f2bf(f1.w);
        *(short8*)&sX[el * LDE + kg * 8] = hv;
    }
    __syncthreads();

    f32x4 acc[4][4];
    #pragma unroll
    for (int mt = 0; mt < 4; ++mt)
        #pragma unroll
        for (int nt = 0; nt < 4; ++nt) acc[mt][nt] = (f32x4){0.f,0.f,0.f,0.f};

    const unsigned short* wb = wtp + half * NHID * NHID;
    #pragma unroll
    for (int kk = 0; kk < 4; ++kk) {
        short8 af[4], bfr[4];
        #pragma unroll
        for (int mt = 0; mt < 4; ++mt) {
            int r = wm * 64 + mt * 16 + l15;
            af[mt] = *(const short8*)(&sX[r * LDE + kk * 32 + l4 * 8]);
        }
        #pragma unroll
        for (int nt = 0; nt < 4; ++nt) {
            int n = wn * 64 + nt * 16 + l15;
            bfr[nt] = *(const short8*)(wb + n * NHID + kk * 32 + l4 * 8);
        }
        #pragma unroll
        for (int mt = 0; mt < 4; ++mt)
            #pragma unroll
            for (int nt = 0; nt < 4; ++nt)
                acc[mt][nt] = __builtin_amdgcn_mfma_f32_16x16x32_bf16(
                    af[mt], bfr[nt], acc[mt][nt], 0, 0, 0);
    }

    // write bf16: one ushort4 per (mt, r) at permuted offset l15*4 (+nt inside)
    #pragma unroll
    for (int mt = 0; mt < 4; ++mt) {
        int rbase = wm * 64 + mt * 16 + l4 * 4;
        #pragma unroll
        for (int r = 0; r < 4; ++r) {
            int n = n0 + rbase + r;
            if (n < N) {
                ushort4v v;
                #pragma unroll
                for (int nt = 0; nt < 4; ++nt) v[nt] = f2bf(acc[mt][nt][r]);
                *(ushort4v*)(xp + (size_t)n * 256 + half * NHID + wn * 64 + l15 * 4) = v;
            }
        }
    }
}

// ---- main: per 128-edge tile ----
__global__ __launch_bounds__(256, 4) void edge_conv_kernel(
    const float* __restrict__ eattr,
    const int* __restrict__ ip,
    const float* __restrict__ bmsg, const float* __restrict__ bedge,
    const unsigned short* __restrict__ wt3,
    const unsigned short* __restrict__ wte,
    const unsigned short* __restrict__ xp,
    const int* __restrict__ flag,
    float* __restrict__ out, int E)
{
    __shared__ __align__(16) unsigned short sEA[BM * LDE];  // 34816 B
    __shared__ int sIdx[2 * BM];                            // 1024 B

    const int tid  = threadIdx.x;
    const int lane = tid & 63;
    const int wave = tid >> 6;
    const int wm   = wave >> 1, wn = wave & 1;
    const int l15  = lane & 15, l4 = lane >> 4;
    const int e0   = blockIdx.x * BM;
    const int is64 = flag[0];

    // edge indices (low words if int64)
    {
        int t = tid;
        if (t < BM) {
            int e = e0 + t; if (e >= E) e = E - 1;
            sIdx[t] = is64 ? ip[2 * (long long)e] : ip[e];
        } else {
            int e = e0 + (t - BM); if (e >= E) e = E - 1;
            long long off = (long long)E + e;
            sIdx[t] = is64 ? ip[2 * off] : ip[off];
        }
    }

    // stage edge_attr fp32 -> bf16 (contiguous 64 KB block read)
    const int erow = tid >> 4, kg = tid & 15;
    #pragma unroll
    for (int p = 0; p < 8; ++p) {
        int el = p * 16 + erow;
        int e  = e0 + el; if (e >= E) e = E - 1;
        const float4* sp = (const float4*)(eattr + (size_t)e * NHID + kg * 8);
        float4 f0 = sp[0], f1 = sp[1];
        short8 hv;
        hv[0] = (short)f2bf(f0.x); hv[1] = (short)f2bf(f0.y);
        hv[2] = (short)f2bf(f0.z); hv[3] = (short)f2bf(f0.w);
        hv[4] = (short)f2bf(f1.x); hv[5] = (short)f2bf(f1.y);
        hv[6] = (short)f2bf(f1.z); hv[7] = (short)f2bf(f1.w);
        *(short8*)&sEA[el * LDE + kg * 8] = hv;
    }
    __syncthreads();

    f32x4 acc[4][4];
    #pragma unroll
    for (int mt = 0; mt < 4; ++mt)
        #pragma unroll
        for (int nt = 0; nt < 4; ++nt) acc[mt][nt] = (f32x4){0.f,0.f,0.f,0.f};

    // GEMM1': edge_attr @ W3   (K = 128)
    #pragma unroll
    for (int kk = 0; kk < 4; ++kk) {
        short8 af[4], bfr[4];
        #pragma unroll
        for (int mt = 0; mt < 4; ++mt) {
            int r = wm * 64 + mt * 16 + l15;
            af[mt] = *(const short8*)(&sEA[r * LDE + kk * 32 + l4 * 8]);
        }
        #pragma unroll
        for (int nt = 0; nt < 4; ++nt) {
            int n = wn * 64 + nt * 16 + l15;
            bfr[nt] = *(const short8*)(wt3 + n * NHID + kk * 32 + l4 * 8);
        }
        #pragma unroll
        for (int mt = 0; mt < 4; ++mt)
            #pragma unroll
            for (int nt = 0; nt < 4; ++nt)
                acc[mt][nt] = __builtin_amdgcn_mfma_f32_16x16x32_bf16(
                    af[mt], bfr[nt], acc[mt][nt], 0, 0, 0);
    }
    __syncthreads();   // all waves done reading sEA before epilogue rewrites it

    // epilogue 1: ea = edge_attr + relu(acc + b_msg + Xp1[row] + Xp2[col])
    // permuted xp layout -> ONE ushort4 per row-half (32 loads/thread vs 128)
    {
        float bm_[4];
        #pragma unroll
        for (int nt = 0; nt < 4; ++nt) bm_[nt] = bmsg[wn * 64 + nt * 16 + l15];
        #pragma unroll
        for (int mt = 0; mt < 4; ++mt) {
            int rbase = wm * 64 + mt * 16 + l4 * 4;
            ushort4v p1[4], p2[4];
            #pragma unroll
            for (int r = 0; r < 4; ++r) {
                int row = rbase + r;
                int nr  = sIdx[row];
                int ncl = sIdx[BM + row];
                p1[r] = *(const ushort4v*)(xp + (size_t)nr  * 256 + wn * 64 + l15 * 4);
                p2[r] = *(const ushort4v*)(xp + (size_t)ncl * 256 + 128 + wn * 64 + l15 * 4);
            }
            #pragma unroll
            for (int r = 0; r < 4; ++r) {
                int row = rbase + r;
                #pragma unroll
                for (int nt = 0; nt < 4; ++nt) {
                    float m = acc[mt][nt][r] + bm_[nt]
                            + bf2f(p1[r][nt]) + bf2f(p2[r][nt]);
                    m = fmaxf(m, 0.f);
                    int idx = row * LDE + wn * 64 + nt * 16 + l15;
                    sEA[idx] = f2bf(bf2f(sEA[idx]) + m);
                    acc[mt][nt][r] = 0.f;
                }
            }
        }
    }
    __syncthreads();

    // GEMM2: ea @ W_edge   (K = 128)
    #pragma unroll
    for (int kk = 0; kk < 4; ++kk) {
        short8 af[4], bfr[4];
        #pragma unroll
        for (int mt = 0; mt < 4; ++mt) {
            int r = wm * 64 + mt * 16 + l15;
            af[mt] = *(const short8*)(&sEA[r * LDE + kk * 32 + l4 * 8]);
        }
        #pragma unroll
        for (int nt = 0; nt < 4; ++nt) {
            int n = wn * 64 + nt * 16 + l15;
            bfr[nt] = *(const short8*)(wte + n * NHID + kk * 32 + l4 * 8);
        }
        #pragma unroll
        for (int mt = 0; mt < 4; ++mt)
            #pragma unroll
            for (int nt = 0; nt < 4; ++nt)
                acc[mt][nt] = __builtin_amdgcn_mfma_f32_16x16x32_bf16(
                    af[mt], bfr[nt], acc[mt][nt], 0, 0, 0);
    }

    // epilogue 2: out = relu(acc + b_edge)  (plain stores — NT hurt WRITE_SIZE)
    {
        float bb[4];
        #pragma unroll
        for (int nt = 0; nt < 4; ++nt) bb[nt] = bedge[wn * 64 + nt * 16 + l15];
        #pragma unroll
        for (int mt = 0; mt < 4; ++mt) {
            int rbase = wm * 64 + mt * 16 + l4 * 4;
            #pragma unroll
            for (int r = 0; r < 4; ++r) {
                int e = e0 + rbase + r;
                if (e < E) {
                    float* op = out + (size_t)e * NHID + wn * 64 + l15;
                    #pragma unroll
                    for (int nt = 0; nt < 4; ++nt)
                        op[nt * 16] = fmaxf(acc[mt][nt][r] + bb[nt], 0.f);
                }
            }
        }
    }
}

extern "C" void kernel_launch(void* const* d_in, const int* in_sizes, int n_in,
                              void* d_out, int out_size, void* d_ws, size_t ws_size,
                              hipStream_t stream) {
    const float* x     = (const float*)d_in[0];
    const float* eattr = (const float*)d_in[1];
    const int*   eidx  = (const int*)d_in[2];
    const float* Wm    = (const float*)d_in[3];
    const float* bm    = (const float*)d_in[4];
    const float* We    = (const float*)d_in[5];
    const float* be    = (const float*)d_in[6];
    float* out = (float*)d_out;

    const int N = in_sizes[0] / NHID;
    const int E = in_sizes[2] / 2;

    unsigned short* wtp = (unsigned short*)d_ws;        // 256*128
    unsigned short* wt3 = wtp + 256 * NHID;             // 128*128
    unsigned short* wte = wt3 + NHID * NHID;            // 128*128
    int* flag = (int*)(wte + NHID * NHID);
    unsigned short* xp  = (unsigned short*)(flag + 4);  // N*256 bf16 (~51 MB)

    prep_kernel<<<(256 * NHID + 255) / 256, 256, 0, stream>>>(Wm, We, eidx, wtp, wt3, wte, flag);

    dim3 pgrid((N + BM - 1) / BM, 2);
    proj_kernel<<<pgrid, 256, 0, stream>>>(x, wtp, xp, N);

    int nblocks = (E + BM - 1) / BM;
    edge_conv_kernel<<<nblocks, 256, 0, stream>>>(eattr, eidx, bm, be,
                                                  wt3, wte, xp, flag, out, E);
}